// Round 1
// baseline (45430.383 us; speedup 1.0000x reference)
//
#include <hip/hip_runtime.h>
#include <math.h>

#define PITCH 65
#define SW_BATCH 9
#define SW_SMALL 10
#define NPART 32

// ---- workspace float-offsets ----
#define OFF_ACCG 0
#define OFF_ACCT (NPART*4096)
#define OFF_BASE (2*NPART*4096)
#define SL_MNH  (OFF_BASE + 0*4096)
#define SL_MH   (OFF_BASE + 1*4096)
#define SL_WH   (OFF_BASE + 2*4096)
#define SL_P    (OFF_BASE + 3*4096)
#define SL_Q    (OFF_BASE + 4*4096)
#define SL_GH   (OFF_BASE + 5*4096)
#define SL_GNH  (OFF_BASE + 6*4096)
#define SL_MNH2 (OFF_BASE + 7*4096)
#define OFF_VAR (OFF_BASE + 8*4096)
#define SL_SC   (OFF_BASE + 8*4096 + 1)

struct Smem {
  float S0[64*PITCH], S1[64*PITCH], S2[64*PITCH];
  float w[64], w2[64];
  float cc[32], ss[32];
  int   pp[32], qq[32];
  float red[256];
};

// ---------- LDS <-> global helpers (blockDim.x == 256) ----------
__device__ __forceinline__ void g2s(float* dst, const float* __restrict__ src) {
  int t = threadIdx.x;
#pragma unroll
  for (int i = 0; i < 16; ++i) {
    int e = t + (i << 8);
    dst[(e >> 6) * PITCH + (e & 63)] = src[e];
  }
  __syncthreads();
}
__device__ __forceinline__ void g2s_scaled(float* dst, const float* __restrict__ src, float sc) {
  int t = threadIdx.x;
#pragma unroll
  for (int i = 0; i < 16; ++i) {
    int e = t + (i << 8);
    dst[(e >> 6) * PITCH + (e & 63)] = src[e] * sc;
  }
  __syncthreads();
}
__device__ __forceinline__ void s2g(float* __restrict__ dst, const float* src) {
  int t = threadIdx.x;
#pragma unroll
  for (int i = 0; i < 16; ++i) {
    int e = t + (i << 8);
    dst[e] = src[(e >> 6) * PITCH + (e & 63)];
  }
  __syncthreads();
}
__device__ __forceinline__ void scpy(float* dst, const float* src) {
  int t = threadIdx.x;
#pragma unroll
  for (int i = 0; i < 16; ++i) {
    int e = t + (i << 8);
    int idx = (e >> 6) * PITCH + (e & 63);
    dst[idx] = src[idx];
  }
  __syncthreads();
}

// ---------- 64x64 matmul: C = A*B or A*B^T (LDS, pitch 65) ----------
// C must not alias A or B. Each thread: 16 outputs (column j, rows r0..r0+15).
template<bool TRANSB>
__device__ void mm(float* C, const float* A, const float* B) {
  int t = threadIdx.x;
  int j = t & 63, r0 = (t >> 6) << 4;
  float acc[16];
#pragma unroll
  for (int r = 0; r < 16; ++r) acc[r] = 0.f;
  for (int k = 0; k < 64; ++k) {
    float b = TRANSB ? B[j * PITCH + k] : B[k * PITCH + j];
#pragma unroll
    for (int r = 0; r < 16; ++r)
      acc[r] = fmaf(A[(r0 + r) * PITCH + k], b, acc[r]);
  }
#pragma unroll
  for (int r = 0; r < 16; ++r) C[(r0 + r) * PITCH + j] = acc[r];
  __syncthreads();
}

// same but writes C to global (row-major 64x64)
template<bool TRANSB>
__device__ void mm_g(float* __restrict__ Cg, const float* A, const float* B) {
  int t = threadIdx.x;
  int j = t & 63, r0 = (t >> 6) << 4;
  float acc[16];
#pragma unroll
  for (int r = 0; r < 16; ++r) acc[r] = 0.f;
  for (int k = 0; k < 64; ++k) {
    float b = TRANSB ? B[j * PITCH + k] : B[k * PITCH + j];
#pragma unroll
    for (int r = 0; r < 16; ++r)
      acc[r] = fmaf(A[(r0 + r) * PITCH + k], b, acc[r]);
  }
#pragma unroll
  for (int r = 0; r < 16; ++r) Cg[(r0 + r) * 64 + j] = acc[r];
  __syncthreads();
}

// ---------- C = V * diag(wv) * V^T ; C must not alias V ----------
__device__ void recon(float* C, const float* V, const float* wv) {
  __syncthreads();  // make w2 writes visible
  int t = threadIdx.x;
  int j = t & 63, r0 = (t >> 6) << 4;
  float acc[16];
#pragma unroll
  for (int r = 0; r < 16; ++r) acc[r] = 0.f;
  for (int k = 0; k < 64; ++k) {
    float b = wv[k] * V[j * PITCH + k];
#pragma unroll
    for (int r = 0; r < 16; ++r)
      acc[r] = fmaf(V[(r0 + r) * PITCH + k], b, acc[r]);
  }
#pragma unroll
  for (int r = 0; r < 16; ++r) C[(r0 + r) * PITCH + j] = acc[r];
  __syncthreads();
}

// ---------- parallel-order cyclic Jacobi eigensolver, 64x64 symmetric ----------
// A (destroyed, diagonal -> sm.w), V <- eigenvectors (A0 = V diag(w) V^T)
__device__ void eig64(Smem& sm, float* A, float* V, int sweeps) {
  int t = threadIdx.x;
  int lane = t & 63, r0 = (t >> 6) << 4;
  float p1 = 0.f;
#pragma unroll
  for (int r = 0; r < 16; ++r) {
    int row = r0 + r;
    V[row * PITCH + lane] = (row == lane) ? 1.f : 0.f;
    float a = A[row * PITCH + lane];
    p1 += a * a;
  }
  sm.red[t] = p1;
  __syncthreads();
  for (int ofs = 128; ofs > 0; ofs >>= 1) {
    if (t < ofs) sm.red[t] += sm.red[t + ofs];
    __syncthreads();
  }
  const float tol = 1e-7f * sqrtf(sm.red[0]) + 1e-30f;

  for (int s = 0; s < sweeps; ++s) {
    for (int r = 0; r < 63; ++r) {
      // --- rotation parameters for the 32 disjoint pairs of this round ---
      if (t < 32) {
        int p_, q_;
        if (t == 0) { p_ = 63; q_ = r; }
        else {
          int a = r + t;       if (a >= 63) a -= 63;
          int b = r + 63 - t;  if (b >= 63) b -= 63;
          p_ = a; q_ = b;
        }
        float app = A[p_ * PITCH + p_];
        float aqq = A[q_ * PITCH + q_];
        float apq = A[p_ * PITCH + q_];
        float c = 1.f, sn = 0.f;
        if (fabsf(apq) > tol) {
          float tau = (aqq - app) / (2.f * apq);
          float tt = 1.f / (fabsf(tau) + sqrtf(1.f + tau * tau));
          if (tau < 0.f) tt = -tt;
          c = rsqrtf(1.f + tt * tt);
          sn = tt * c;
        }
        sm.cc[t] = c; sm.ss[t] = sn;
        sm.pp[t] = p_; sm.qq[t] = q_;
      }
      __syncthreads();
      // --- row phase: A <- J^T A  (wave-uniform k => uniform skip branch) ---
#pragma unroll
      for (int m = 0; m < 8; ++m) {
        int k = ((t >> 6) << 3) + m;
        float sn = sm.ss[k];
        if (sn != 0.f) {
          float c = sm.cc[k];
          int p_ = sm.pp[k], q_ = sm.qq[k];
          float ap = A[p_ * PITCH + lane], aq = A[q_ * PITCH + lane];
          A[p_ * PITCH + lane] = c * ap - sn * aq;
          A[q_ * PITCH + lane] = sn * ap + c * aq;
        }
      }
      __syncthreads();
      // --- col phase: A <- A J ; V <- V J ---
#pragma unroll
      for (int m = 0; m < 8; ++m) {
        int k = ((t >> 6) << 3) + m;
        float sn = sm.ss[k];
        if (sn != 0.f) {
          float c = sm.cc[k];
          int p_ = sm.pp[k], q_ = sm.qq[k];
          float ap = A[lane * PITCH + p_], aq = A[lane * PITCH + q_];
          A[lane * PITCH + p_] = c * ap - sn * aq;
          A[lane * PITCH + q_] = sn * ap + c * aq;
          float vp = V[lane * PITCH + p_], vq = V[lane * PITCH + q_];
          V[lane * PITCH + p_] = c * vp - sn * vq;
          V[lane * PITCH + q_] = sn * vp + c * vq;
        }
      }
      __syncthreads();
    }
  }
  if (t < 64) sm.w[t] = A[t * PITCH + t];
  __syncthreads();
}

// ============================ kernels ============================

__global__ __launch_bounds__(256) void kzero(float* ws) {
  int i = blockIdx.x * 256 + threadIdx.x;
  if (i < OFF_BASE) ws[i] = 0.f;
  if (i == 0) ws[OFF_VAR] = 0.f;
}

// eig(M) -> Mnh, Mh ; eig(W) -> Wh ; Wc = Mnh Wh Mnh ; eig(Wc);
// P = Wc^{-1/2} Wh ; Q = Mh Wc^{1/2}
__global__ __launch_bounds__(256) void kprep(const float* __restrict__ weight,
                                             const float* __restrict__ M,
                                             float* ws) {
  __shared__ Smem sm;
  int t = threadIdx.x;
  g2s(sm.S0, M);
  eig64(sm, sm.S0, sm.S1, SW_SMALL);
  if (t < 64) sm.w2[t] = rsqrtf(fmaxf(sm.w[t], 1e-12f));
  recon(sm.S2, sm.S1, sm.w2);
  s2g(ws + SL_MNH, sm.S2);
  if (t < 64) sm.w2[t] = sqrtf(fmaxf(sm.w[t], 0.f));
  recon(sm.S2, sm.S1, sm.w2);
  s2g(ws + SL_MH, sm.S2);

  g2s(sm.S0, weight);
  eig64(sm, sm.S0, sm.S1, SW_SMALL);
  if (t < 64) sm.w2[t] = sqrtf(fmaxf(sm.w[t], 0.f));
  recon(sm.S2, sm.S1, sm.w2);          // Wh in S2
  s2g(ws + SL_WH, sm.S2);

  g2s(sm.S0, ws + SL_MNH);
  mm<false>(sm.S1, sm.S0, sm.S2);      // Mnh*Wh
  mm<false>(sm.S2, sm.S1, sm.S0);      // Wc
  scpy(sm.S0, sm.S2);
  eig64(sm, sm.S0, sm.S1, SW_SMALL);
  if (t < 64) sm.w2[t] = rsqrtf(fmaxf(sm.w[t], 1e-12f));
  recon(sm.S0, sm.S1, sm.w2);          // Wc^{-1/2}
  g2s(sm.S2, ws + SL_WH);
  mm_g<false>(ws + SL_P, sm.S0, sm.S2);   // P = Wcnh*Wh
  if (t < 64) sm.w2[t] = sqrtf(fmaxf(sm.w[t], 0.f));
  recon(sm.S0, sm.S1, sm.w2);          // Wc^{1/2}
  g2s(sm.S2, ws + SL_MH);
  mm_g<false>(ws + SL_Q, sm.S2, sm.S0);   // Q = Mh*Wch
}

// Xc_i = Mnh sqrt(X_i) Mnh -> out ; accumulate sum(Xc)
__global__ __launch_bounds__(256) void k1(const float* __restrict__ X,
                                          float* __restrict__ out, float* ws) {
  __shared__ Smem sm;
  int t = threadIdx.x;
  size_t b = blockIdx.x;
  g2s(sm.S0, X + b * 4096);
  eig64(sm, sm.S0, sm.S1, SW_BATCH);
  if (t < 64) sm.w2[t] = sqrtf(fmaxf(sm.w[t], 0.f));
  recon(sm.S0, sm.S1, sm.w2);          // Xp
  g2s(sm.S2, ws + SL_MNH);
  mm<false>(sm.S1, sm.S2, sm.S0);      // Mnh*Xp
  mm<false>(sm.S0, sm.S1, sm.S2);      // Xc
  float* Xc = out + b * 4096;
  float* acc = ws + OFF_ACCG + (size_t)(blockIdx.x & (NPART - 1)) * 4096;
#pragma unroll
  for (int i = 0; i < 16; ++i) {
    int e = t + (i << 8);
    float v = sm.S0[(e >> 6) * PITCH + (e & 63)];
    Xc[e] = v;
    atomicAdd(acc + e, v);
  }
}

// G0 = mean(Xc); eig -> G0h, G0nh
__global__ __launch_bounds__(256) void ksmall2(float* ws, float invB) {
  __shared__ Smem sm;
  int t = threadIdx.x;
#pragma unroll
  for (int i = 0; i < 16; ++i) {
    int e = t + (i << 8);
    float sum = 0.f;
    for (int p = 0; p < NPART; ++p) sum += ws[OFF_ACCG + p * 4096 + e];
    sm.S0[(e >> 6) * PITCH + (e & 63)] = sum * invB;
  }
  __syncthreads();
  eig64(sm, sm.S0, sm.S1, SW_SMALL);
  if (t < 64) sm.w2[t] = sqrtf(fmaxf(sm.w[t], 0.f));
  recon(sm.S2, sm.S1, sm.w2);
  s2g(ws + SL_GH, sm.S2);
  if (t < 64) sm.w2[t] = rsqrtf(fmaxf(sm.w[t], 1e-12f));
  recon(sm.S2, sm.S1, sm.w2);
  s2g(ws + SL_GNH, sm.S2);
}

// accumulate sum_i log(G0nh Xc_i G0nh)
__global__ __launch_bounds__(256) void k2(const float* __restrict__ XcBuf, float* ws) {
  __shared__ Smem sm;
  int t = threadIdx.x;
  size_t b = blockIdx.x;
  g2s(sm.S0, XcBuf + b * 4096);
  g2s(sm.S2, ws + SL_GNH);
  mm<false>(sm.S1, sm.S2, sm.S0);
  mm<false>(sm.S0, sm.S1, sm.S2);
  eig64(sm, sm.S0, sm.S1, SW_BATCH);
  if (t < 64) sm.w2[t] = logf(fmaxf(sm.w[t], 1e-12f));
  recon(sm.S2, sm.S1, sm.w2);
  float* acc = ws + OFF_ACCT + (size_t)(blockIdx.x & (NPART - 1)) * 4096;
#pragma unroll
  for (int i = 0; i < 16; ++i) {
    int e = t + (i << 8);
    atomicAdd(acc + e, sm.S2[(e >> 6) * PITCH + (e & 63)]);
  }
}

// Tbar = mean ; mean_G = G0h exp(Tbar) G0h ; mnh = mean_G^{-1/2}
__global__ __launch_bounds__(256) void ksmall3(float* ws, float invB) {
  __shared__ Smem sm;
  int t = threadIdx.x;
#pragma unroll
  for (int i = 0; i < 16; ++i) {
    int e = t + (i << 8);
    float sum = 0.f;
    for (int p = 0; p < NPART; ++p) sum += ws[OFF_ACCT + p * 4096 + e];
    sm.S0[(e >> 6) * PITCH + (e & 63)] = sum * invB;
  }
  __syncthreads();
  eig64(sm, sm.S0, sm.S1, SW_SMALL);
  if (t < 64) sm.w2[t] = expf(sm.w[t]);
  recon(sm.S2, sm.S1, sm.w2);          // E
  g2s(sm.S0, ws + SL_GH);
  mm<false>(sm.S1, sm.S0, sm.S2);      // GH*E
  mm<false>(sm.S2, sm.S1, sm.S0);      // mean_G
  scpy(sm.S0, sm.S2);
  eig64(sm, sm.S0, sm.S1, SW_SMALL);
  if (t < 64) sm.w2[t] = rsqrtf(fmaxf(sm.w[t], 1e-12f));
  recon(sm.S2, sm.S1, sm.w2);
  s2g(ws + SL_MNH2, sm.S2);
}

// T_i = log(mnh Xc_i mnh) (overwrites Xc in buf) ; accumulate ||T||_F^2
__global__ __launch_bounds__(256) void k3(float* __restrict__ buf, float* ws) {
  __shared__ Smem sm;
  int t = threadIdx.x;
  size_t b = blockIdx.x;
  g2s(sm.S0, buf + b * 4096);
  g2s(sm.S2, ws + SL_MNH2);
  mm<false>(sm.S1, sm.S2, sm.S0);
  mm<false>(sm.S0, sm.S1, sm.S2);
  eig64(sm, sm.S0, sm.S1, SW_BATCH);
  if (t < 64) sm.w2[t] = logf(fmaxf(sm.w[t], 1e-12f));
  recon(sm.S2, sm.S1, sm.w2);          // T
  float ssq = 0.f;
  float* Tg = buf + b * 4096;
#pragma unroll
  for (int i = 0; i < 16; ++i) {
    int e = t + (i << 8);
    float v = sm.S2[(e >> 6) * PITCH + (e & 63)];
    Tg[e] = v;
    ssq += v * v;
  }
  sm.red[t] = ssq;
  __syncthreads();
  for (int ofs = 128; ofs > 0; ofs >>= 1) {
    if (t < ofs) sm.red[t] += sm.red[t + ofs];
    __syncthreads();
  }
  if (t == 0) atomicAdd(ws + OFF_VAR, sm.red[0]);
}

__global__ void kscale(float* ws, const float* __restrict__ shift, float invB) {
  if (threadIdx.x == 0 && blockIdx.x == 0) {
    float var = ws[OFF_VAR] * invB;
    ws[SL_SC] = shift[0] / sqrtf(var + 1e-5f);
  }
}

// Y_i = (Q exp(scale * P T_i P^T) Q^T)^2  -> out (in place over T)
__global__ __launch_bounds__(256) void k4(float* __restrict__ buf, float* ws) {
  __shared__ Smem sm;
  int t = threadIdx.x;
  size_t b = blockIdx.x;
  float sc = ws[SL_SC];
  g2s_scaled(sm.S0, buf + b * 4096, sc);   // scale * T
  g2s(sm.S2, ws + SL_P);
  mm<false>(sm.S1, sm.S2, sm.S0);          // P*T
  mm<true >(sm.S0, sm.S1, sm.S2);          // (P*T)*P^T
  eig64(sm, sm.S0, sm.S1, SW_BATCH);
  if (t < 64) sm.w2[t] = expf(sm.w[t]);
  recon(sm.S2, sm.S1, sm.w2);              // E
  g2s(sm.S0, ws + SL_Q);
  mm<false>(sm.S1, sm.S0, sm.S2);          // Q*E
  mm<true >(sm.S2, sm.S1, sm.S0);          // Z = Q E Q^T
  mm<false>(sm.S0, sm.S2, sm.S2);          // Z*Z  (sym_pow(.,2))
  s2g(buf + b * 4096, sm.S0);
}

extern "C" void kernel_launch(void* const* d_in, const int* in_sizes, int n_in,
                              void* d_out, int out_size, void* d_ws, size_t ws_size,
                              hipStream_t stream) {
  const float* X      = (const float*)d_in[0];
  const float* weight = (const float*)d_in[1];
  const float* M      = (const float*)d_in[2];
  const float* shift  = (const float*)d_in[3];
  float* out = (float*)d_out;
  float* ws  = (float*)d_ws;
  int B = in_sizes[0] / 4096;      // 4096 matrices of 64x64
  float invB = 1.f / (float)B;

  hipLaunchKernelGGL(kzero,   dim3(OFF_BASE / 256), dim3(256), 0, stream, ws);
  hipLaunchKernelGGL(kprep,   dim3(1), dim3(256), 0, stream, weight, M, ws);
  hipLaunchKernelGGL(k1,      dim3(B), dim3(256), 0, stream, X, out, ws);
  hipLaunchKernelGGL(ksmall2, dim3(1), dim3(256), 0, stream, ws, invB);
  hipLaunchKernelGGL(k2,      dim3(B), dim3(256), 0, stream, out, ws);
  hipLaunchKernelGGL(ksmall3, dim3(1), dim3(256), 0, stream, ws, invB);
  hipLaunchKernelGGL(k3,      dim3(B), dim3(256), 0, stream, out, ws);
  hipLaunchKernelGGL(kscale,  dim3(1), dim3(64), 0, stream, ws, shift, invB);
  hipLaunchKernelGGL(k4,      dim3(B), dim3(256), 0, stream, out, ws);
}

// Round 2
// 21454.784 us; speedup vs baseline: 2.1175x; 2.1175x over previous
//
#include <hip/hip_runtime.h>
#include <math.h>

#define PITCH 65
#define SW_BATCH 9
#define SW_SMALL 10
#define NPART 32

// ---- workspace float-offsets ----
#define OFF_ACCG 0
#define OFF_ACCT (NPART*4096)
#define OFF_BASE (2*NPART*4096)
#define SL_MNH  (OFF_BASE + 0*4096)
#define SL_MH   (OFF_BASE + 1*4096)
#define SL_WH   (OFF_BASE + 2*4096)
#define SL_P    (OFF_BASE + 3*4096)
#define SL_Q    (OFF_BASE + 4*4096)
#define SL_GH   (OFF_BASE + 5*4096)
#define SL_GNH  (OFF_BASE + 6*4096)
#define SL_MNH2 (OFF_BASE + 7*4096)
#define SL_WCH  (OFF_BASE + 8*4096)
#define OFF_VAR (OFF_BASE + 9*4096)
#define SL_SC   (OFF_BASE + 9*4096 + 1)

struct Smem {
  float4 par[32];                 // (c, s, p, q) per rotation pair
  float S0[64*PITCH], S1[64*PITCH];
  float w[64], w2[64];
  float red[256];
  int flag;
};

// ---------- LDS <-> global helpers (blockDim.x == 256) ----------
__device__ __forceinline__ void g2s(float* dst, const float* __restrict__ src) {
  int t = threadIdx.x;
#pragma unroll
  for (int i = 0; i < 16; ++i) {
    int e = t + (i << 8);
    dst[(e >> 6) * PITCH + (e & 63)] = src[e];
  }
  __syncthreads();
}
__device__ __forceinline__ void g2s_scaled(float* dst, const float* __restrict__ src, float sc) {
  int t = threadIdx.x;
#pragma unroll
  for (int i = 0; i < 16; ++i) {
    int e = t + (i << 8);
    dst[(e >> 6) * PITCH + (e & 63)] = src[e] * sc;
  }
  __syncthreads();
}
__device__ __forceinline__ void s2g(float* __restrict__ dst, const float* src) {
  int t = threadIdx.x;
#pragma unroll
  for (int i = 0; i < 16; ++i) {
    int e = t + (i << 8);
    dst[e] = src[(e >> 6) * PITCH + (e & 63)];
  }
  __syncthreads();
}

// ---------- in-place 64x64 matmuls on LDS (2-buffer choreography) ----------
// Every thread reads ALL needed S0 data before the pre-store barrier, so
// overwriting S0 afterwards is race-free.

// S0 <- S1 * S0
__device__ void mmL(Smem& sm) {
  int t = threadIdx.x;
  int j = t & 63, r0 = (t >> 6) << 4;
  float acc[16];
#pragma unroll
  for (int r = 0; r < 16; ++r) acc[r] = 0.f;
  for (int k = 0; k < 64; ++k) {
    float b = sm.S0[k * PITCH + j];
#pragma unroll
    for (int r = 0; r < 16; ++r)
      acc[r] = fmaf(sm.S1[(r0 + r) * PITCH + k], b, acc[r]);
  }
  __syncthreads();
#pragma unroll
  for (int r = 0; r < 16; ++r) sm.S0[(r0 + r) * PITCH + j] = acc[r];
  __syncthreads();
}

// S0 <- S0 * S1   (or S0 * S1^T)
template<bool TRANSB>
__device__ void mmR(Smem& sm) {
  int t = threadIdx.x;
  int j = t & 63, r0 = (t >> 6) << 4;
  float acc[16];
#pragma unroll
  for (int r = 0; r < 16; ++r) acc[r] = 0.f;
  for (int k = 0; k < 64; ++k) {
    float b = TRANSB ? sm.S1[j * PITCH + k] : sm.S1[k * PITCH + j];
#pragma unroll
    for (int r = 0; r < 16; ++r)
      acc[r] = fmaf(sm.S0[(r0 + r) * PITCH + k], b, acc[r]);
  }
  __syncthreads();
#pragma unroll
  for (int r = 0; r < 16; ++r) sm.S0[(r0 + r) * PITCH + j] = acc[r];
  __syncthreads();
}

// S0 <- S0 * S0
__device__ void mmSq(Smem& sm) {
  int t = threadIdx.x;
  int j = t & 63, r0 = (t >> 6) << 4;
  float acc[16];
#pragma unroll
  for (int r = 0; r < 16; ++r) acc[r] = 0.f;
  for (int k = 0; k < 64; ++k) {
    float b = sm.S0[k * PITCH + j];
#pragma unroll
    for (int r = 0; r < 16; ++r)
      acc[r] = fmaf(sm.S0[(r0 + r) * PITCH + k], b, acc[r]);
  }
  __syncthreads();
#pragma unroll
  for (int r = 0; r < 16; ++r) sm.S0[(r0 + r) * PITCH + j] = acc[r];
  __syncthreads();
}

// S0 <- S1 * diag(w2) * S1^T   (reads only S1/w2; S0 content is dead)
__device__ void reconIP(Smem& sm) {
  __syncthreads();   // w2 visibility
  int t = threadIdx.x;
  int j = t & 63, r0 = (t >> 6) << 4;
  float acc[16];
#pragma unroll
  for (int r = 0; r < 16; ++r) acc[r] = 0.f;
  for (int k = 0; k < 64; ++k) {
    float b = sm.w2[k] * sm.S1[j * PITCH + k];
#pragma unroll
    for (int r = 0; r < 16; ++r)
      acc[r] = fmaf(sm.S1[(r0 + r) * PITCH + k], b, acc[r]);
  }
#pragma unroll
  for (int r = 0; r < 16; ++r) sm.S0[(r0 + r) * PITCH + j] = acc[r];
  __syncthreads();
}

// ---------- fused-2x2 parallel-order cyclic Jacobi, 64x64 symmetric ----------
// A = S0 (destroyed; eigenvalues -> sm.w), V = S1 (eigenvectors).
// Round: 32 disjoint pairs tile A into 32x32 2x2 blocks; each thread applies
// G_i * A2x2 * H_j on 4 blocks (each element R/W exactly once per round) and
// the column rotation on 16 V elements. 2 barriers per round.
__device__ void eig64(Smem& sm, int sweeps) {
  float* A = sm.S0;
  float* V = sm.S1;
  int t = threadIdx.x;
  int lane = t & 63, r0 = (t >> 6) << 4;
  float p1 = 0.f;
#pragma unroll
  for (int r = 0; r < 16; ++r) {
    int row = r0 + r;
    V[row * PITCH + lane] = (row == lane) ? 1.f : 0.f;
    float a = A[row * PITCH + lane];
    p1 += a * a;
  }
  if (t == 0) sm.flag = 0;
  sm.red[t] = p1;
  __syncthreads();
  for (int ofs = 128; ofs > 0; ofs >>= 1) {
    if (t < ofs) sm.red[t] += sm.red[t + ofs];
    __syncthreads();
  }
  const float tol = 1e-6f * sqrtf(sm.red[0]) + 1e-30f;

  const int bi  = t >> 3;          // this thread's row-pair block
  const int bj0 = (t & 7) << 2;    // first of 4 col-pair blocks
  const int kv  = t & 31;          // V-update pair
  const int vr0 = (t >> 5) << 3;   // V-update first row

  for (int s = 0; s < sweeps; ++s) {
    for (int r = 0; r < 63; ++r) {
      if (t < 32) {
        int p_, q_;
        if (t == 0) { p_ = 63; q_ = r; }
        else {
          int a = r + t;      if (a >= 63) a -= 63;
          int b = r + 63 - t; if (b >= 63) b -= 63;
          p_ = a; q_ = b;
        }
        float app = A[p_ * PITCH + p_];
        float aqq = A[q_ * PITCH + q_];
        float apq = A[p_ * PITCH + q_];
        float c = 1.f, sn = 0.f;
        if (fabsf(apq) > tol) {
          float tau = (aqq - app) / (2.f * apq);
          float tt = 1.f / (fabsf(tau) + sqrtf(1.f + tau * tau));
          if (tau < 0.f) tt = -tt;
          c = rsqrtf(1.f + tt * tt);
          sn = tt * c;
          sm.flag = 1;
        }
        sm.par[t] = make_float4(c, sn, (float)p_, (float)q_);
      }
      __syncthreads();
      // --- fused A block updates: rows pair bi, cols pairs bj0..bj0+3 ---
      {
        float4 Pi = sm.par[bi];
        float ci = Pi.x, si = Pi.y;
        int rp = (int)Pi.z * PITCH, rq = (int)Pi.w * PITCH;
#pragma unroll
        for (int m = 0; m < 4; ++m) {
          float4 Pj = sm.par[bj0 + m];
          float cj = Pj.x, sj = Pj.y;
          if (si == 0.f && sj == 0.f) continue;
          int cp = (int)Pj.z, cq = (int)Pj.w;
          float a00 = A[rp + cp], a01 = A[rp + cq];
          float a10 = A[rq + cp], a11 = A[rq + cq];
          // row rotation (pair i), then column rotation (pair j)
          float b00 = ci * a00 - si * a10, b01 = ci * a01 - si * a11;
          float b10 = si * a00 + ci * a10, b11 = si * a01 + ci * a11;
          A[rp + cp] = cj * b00 - sj * b01;
          A[rp + cq] = sj * b00 + cj * b01;
          A[rq + cp] = cj * b10 - sj * b11;
          A[rq + cq] = sj * b10 + cj * b11;
        }
      }
      // --- V column update: V <- V * J ---
      {
        float4 Pk = sm.par[kv];
        if (Pk.y != 0.f) {
          float c = Pk.x, sn = Pk.y;
          int p_ = (int)Pk.z, q_ = (int)Pk.w;
          int base = vr0 * PITCH;
#pragma unroll
          for (int i = 0; i < 8; ++i) {
            float vp = V[base + p_], vq = V[base + q_];
            V[base + p_] = c * vp - sn * vq;
            V[base + q_] = sn * vp + c * vq;
            base += PITCH;
          }
        }
      }
      __syncthreads();
    }
    // whole-sweep convergence: if no rotation fired, we're done
    int f = sm.flag;
    __syncthreads();
    if (f == 0) break;
    if (t == 0) sm.flag = 0;
    __syncthreads();
  }
  if (t < 64) sm.w[t] = A[t * PITCH + t];
  __syncthreads();
}

// ============================ kernels ============================

__global__ __launch_bounds__(256) void kzero(float* ws) {
  int i = blockIdx.x * 256 + threadIdx.x;
  if (i < OFF_BASE) ws[i] = 0.f;
  if (i == 0) ws[OFF_VAR] = 0.f;
}

// eig(M) -> Mnh, Mh ; eig(W) -> Wh ; Wc = Mnh Wh Mnh ; eig(Wc) -> Wch, Wcnh;
// P = Wc^{-1/2} Wh ; Q = Mh Wc^{1/2}
__global__ __launch_bounds__(256) void kprep(const float* __restrict__ weight,
                                             const float* __restrict__ M,
                                             float* ws) {
  __shared__ Smem sm;
  int t = threadIdx.x;
  g2s(sm.S0, M);
  eig64(sm, SW_SMALL);
  if (t < 64) sm.w2[t] = rsqrtf(fmaxf(sm.w[t], 1e-12f));
  reconIP(sm);
  s2g(ws + SL_MNH, sm.S0);
  if (t < 64) sm.w2[t] = sqrtf(fmaxf(sm.w[t], 0.f));
  reconIP(sm);
  s2g(ws + SL_MH, sm.S0);

  g2s(sm.S0, weight);
  eig64(sm, SW_SMALL);
  if (t < 64) sm.w2[t] = sqrtf(fmaxf(sm.w[t], 0.f));
  reconIP(sm);                     // S0 = Wh
  s2g(ws + SL_WH, sm.S0);

  g2s(sm.S1, ws + SL_MNH);
  mmL(sm);                         // S0 = Mnh*Wh
  mmR<false>(sm);                  // S0 = Wc
  eig64(sm, SW_SMALL);
  if (t < 64) sm.w2[t] = sqrtf(fmaxf(sm.w[t], 0.f));
  reconIP(sm);                     // S0 = Wc^{1/2}
  s2g(ws + SL_WCH, sm.S0);
  if (t < 64) sm.w2[t] = rsqrtf(fmaxf(sm.w[t], 1e-12f));
  reconIP(sm);                     // S0 = Wc^{-1/2}
  g2s(sm.S1, ws + SL_WH);
  mmR<false>(sm);                  // S0 = P = Wcnh*Wh
  s2g(ws + SL_P, sm.S0);

  g2s(sm.S0, ws + SL_WCH);
  g2s(sm.S1, ws + SL_MH);
  mmL(sm);                         // S0 = Q = Mh*Wch
  s2g(ws + SL_Q, sm.S0);
}

// Xc_i = Mnh sqrt(X_i) Mnh -> out ; accumulate sum(Xc)
__global__ __launch_bounds__(256) void k1(const float* __restrict__ X,
                                          float* __restrict__ out, float* ws) {
  __shared__ Smem sm;
  int t = threadIdx.x;
  size_t b = blockIdx.x;
  g2s(sm.S0, X + b * 4096);
  eig64(sm, SW_BATCH);
  if (t < 64) sm.w2[t] = sqrtf(fmaxf(sm.w[t], 0.f));
  reconIP(sm);                     // S0 = Xp
  g2s(sm.S1, ws + SL_MNH);
  mmL(sm);                         // S0 = Mnh*Xp
  mmR<false>(sm);                  // S0 = Xc
  float* Xc = out + b * 4096;
  float* acc = ws + OFF_ACCG + (size_t)(blockIdx.x & (NPART - 1)) * 4096;
#pragma unroll
  for (int i = 0; i < 16; ++i) {
    int e = t + (i << 8);
    float v = sm.S0[(e >> 6) * PITCH + (e & 63)];
    Xc[e] = v;
    atomicAdd(acc + e, v);
  }
}

// G0 = mean(Xc); eig -> G0h, G0nh
__global__ __launch_bounds__(256) void ksmall2(float* ws, float invB) {
  __shared__ Smem sm;
  int t = threadIdx.x;
#pragma unroll
  for (int i = 0; i < 16; ++i) {
    int e = t + (i << 8);
    float sum = 0.f;
    for (int p = 0; p < NPART; ++p) sum += ws[OFF_ACCG + p * 4096 + e];
    sm.S0[(e >> 6) * PITCH + (e & 63)] = sum * invB;
  }
  __syncthreads();
  eig64(sm, SW_SMALL);
  if (t < 64) sm.w2[t] = sqrtf(fmaxf(sm.w[t], 0.f));
  reconIP(sm);
  s2g(ws + SL_GH, sm.S0);
  if (t < 64) sm.w2[t] = rsqrtf(fmaxf(sm.w[t], 1e-12f));
  reconIP(sm);
  s2g(ws + SL_GNH, sm.S0);
}

// accumulate sum_i log(G0nh Xc_i G0nh)
__global__ __launch_bounds__(256) void k2(const float* __restrict__ XcBuf, float* ws) {
  __shared__ Smem sm;
  int t = threadIdx.x;
  size_t b = blockIdx.x;
  g2s(sm.S0, XcBuf + b * 4096);
  g2s(sm.S1, ws + SL_GNH);
  mmL(sm);
  mmR<false>(sm);                  // S0 = Gnh*Xc*Gnh
  eig64(sm, SW_BATCH);
  if (t < 64) sm.w2[t] = logf(fmaxf(sm.w[t], 1e-12f));
  reconIP(sm);
  float* acc = ws + OFF_ACCT + (size_t)(blockIdx.x & (NPART - 1)) * 4096;
#pragma unroll
  for (int i = 0; i < 16; ++i) {
    int e = t + (i << 8);
    atomicAdd(acc + e, sm.S0[(e >> 6) * PITCH + (e & 63)]);
  }
}

// Tbar = mean ; mean_G = G0h exp(Tbar) G0h ; mnh = mean_G^{-1/2}
__global__ __launch_bounds__(256) void ksmall3(float* ws, float invB) {
  __shared__ Smem sm;
  int t = threadIdx.x;
#pragma unroll
  for (int i = 0; i < 16; ++i) {
    int e = t + (i << 8);
    float sum = 0.f;
    for (int p = 0; p < NPART; ++p) sum += ws[OFF_ACCT + p * 4096 + e];
    sm.S0[(e >> 6) * PITCH + (e & 63)] = sum * invB;
  }
  __syncthreads();
  eig64(sm, SW_SMALL);
  if (t < 64) sm.w2[t] = expf(sm.w[t]);
  reconIP(sm);                     // S0 = E
  g2s(sm.S1, ws + SL_GH);
  mmL(sm);                         // S0 = GH*E
  mmR<false>(sm);                  // S0 = mean_G
  eig64(sm, SW_SMALL);
  if (t < 64) sm.w2[t] = rsqrtf(fmaxf(sm.w[t], 1e-12f));
  reconIP(sm);
  s2g(ws + SL_MNH2, sm.S0);
}

// T_i = log(mnh Xc_i mnh) (overwrites Xc in buf) ; accumulate ||T||_F^2
__global__ __launch_bounds__(256) void k3(float* __restrict__ buf, float* ws) {
  __shared__ Smem sm;
  int t = threadIdx.x;
  size_t b = blockIdx.x;
  g2s(sm.S0, buf + b * 4096);
  g2s(sm.S1, ws + SL_MNH2);
  mmL(sm);
  mmR<false>(sm);
  eig64(sm, SW_BATCH);
  if (t < 64) sm.w2[t] = logf(fmaxf(sm.w[t], 1e-12f));
  reconIP(sm);                     // S0 = T
  float ssq = 0.f;
  float* Tg = buf + b * 4096;
#pragma unroll
  for (int i = 0; i < 16; ++i) {
    int e = t + (i << 8);
    float v = sm.S0[(e >> 6) * PITCH + (e & 63)];
    Tg[e] = v;
    ssq += v * v;
  }
  sm.red[t] = ssq;
  __syncthreads();
  for (int ofs = 128; ofs > 0; ofs >>= 1) {
    if (t < ofs) sm.red[t] += sm.red[t + ofs];
    __syncthreads();
  }
  if (t == 0) atomicAdd(ws + OFF_VAR, sm.red[0]);
}

__global__ void kscale(float* ws, const float* __restrict__ shift, float invB) {
  if (threadIdx.x == 0 && blockIdx.x == 0) {
    float var = ws[OFF_VAR] * invB;
    ws[SL_SC] = shift[0] / sqrtf(var + 1e-5f);
  }
}

// Y_i = (Q exp(scale * P T_i P^T) Q^T)^2  -> out (in place over T)
__global__ __launch_bounds__(256) void k4(float* __restrict__ buf, float* ws) {
  __shared__ Smem sm;
  int t = threadIdx.x;
  size_t b = blockIdx.x;
  float sc = ws[SL_SC];
  g2s_scaled(sm.S0, buf + b * 4096, sc);   // scale * T
  g2s(sm.S1, ws + SL_P);
  mmL(sm);                          // P*T
  mmR<true >(sm);                   // (P*T)*P^T
  eig64(sm, SW_BATCH);
  if (t < 64) sm.w2[t] = expf(sm.w[t]);
  reconIP(sm);                      // S0 = E
  g2s(sm.S1, ws + SL_Q);
  mmL(sm);                          // Q*E
  mmR<true >(sm);                   // Z = Q E Q^T
  mmSq(sm);                         // Z*Z  (sym_pow(.,2))
  s2g(buf + b * 4096, sm.S0);
}

extern "C" void kernel_launch(void* const* d_in, const int* in_sizes, int n_in,
                              void* d_out, int out_size, void* d_ws, size_t ws_size,
                              hipStream_t stream) {
  const float* X      = (const float*)d_in[0];
  const float* weight = (const float*)d_in[1];
  const float* M      = (const float*)d_in[2];
  const float* shift  = (const float*)d_in[3];
  float* out = (float*)d_out;
  float* ws  = (float*)d_ws;
  int B = in_sizes[0] / 4096;      // 4096 matrices of 64x64
  float invB = 1.f / (float)B;

  hipLaunchKernelGGL(kzero,   dim3(OFF_BASE / 256), dim3(256), 0, stream, ws);
  hipLaunchKernelGGL(kprep,   dim3(1), dim3(256), 0, stream, weight, M, ws);
  hipLaunchKernelGGL(k1,      dim3(B), dim3(256), 0, stream, X, out, ws);
  hipLaunchKernelGGL(ksmall2, dim3(1), dim3(256), 0, stream, ws, invB);
  hipLaunchKernelGGL(k2,      dim3(B), dim3(256), 0, stream, out, ws);
  hipLaunchKernelGGL(ksmall3, dim3(1), dim3(256), 0, stream, ws, invB);
  hipLaunchKernelGGL(k3,      dim3(B), dim3(256), 0, stream, out, ws);
  hipLaunchKernelGGL(kscale,  dim3(1), dim3(64), 0, stream, ws, shift, invB);
  hipLaunchKernelGGL(k4,      dim3(B), dim3(256), 0, stream, out, ws);
}